// Round 9
// baseline (5897.268 us; speedup 1.0000x reference)
//
#include <hip/hip_runtime.h>

#define DEVI __device__ __forceinline__

typedef __attribute__((ext_vector_type(4))) float f4;
typedef __attribute__((ext_vector_type(2))) long long i64x2;

DEVI unsigned char f2fp8(float x) {
  int p = __builtin_amdgcn_cvt_pk_fp8_f32(x, x, 0, false);
  return (unsigned char)(p & 0xff);
}
DEVI float fp82f(unsigned char b) {
  return __builtin_amdgcn_cvt_f32_fp8((int)b, 0);
}
DEVI float sigmoidf_(float x) { return 1.f / (1.f + __expf(-x)); }
DEVI float tanhf_(float x) {
  float ax = fabsf(x);
  float e = __expf(-2.f * ax);
  float t = (1.f - e) / (1.f + e);
  return x < 0.f ? -t : t;
}

#define GLDS16(g, l) __builtin_amdgcn_global_load_lds( \
    (const __attribute__((address_space(1))) void*)(g), \
    (__attribute__((address_space(3))) void*)(l), 16, 0, 0)

// fp8 e4m3 scaled by 64; acc = 4096*z; epilogue multiplies by 1/4096.
#define SCALE_UP 64.0f
#define SCALE_DN (1.0f / 4096.0f)

// r6 storage layout (proven 0-conflict), 64B k-blocks:
//  granule interleave: logical 8B granule g at 16B-chunk c1=g&3, half=(g>>2)
//  bank swizzle: physical chunk c2 = c1 ^ ((row>>1)&3)
DEVI int mapcol(int k, int r) {
  int c2 = ((k >> 3) & 3) ^ ((r >> 1) & 3);
  return (k & ~63) | (c2 << 4) | (((k >> 5) & 1) << 3) | (k & 7);
}

// ---------------- conversion kernels (r6) ----------------

__global__ void k_conv_emb(const float* __restrict__ emb, unsigned char* __restrict__ ep) {
  int i = blockIdx.x * 256 + threadIdx.x;            // 10000 * 128
  if (i >= 10000 * 128) return;
  int r = i >> 7, c = i & 127;
  ep[r * 128 + mapcol(c, 0)] =
      (c < 100) ? f2fp8(emb[r * 100 + c] * SCALE_UP) : (unsigned char)0;
}

// column permutation: original col n = gate*1024 + u  ->
// n' = (u/32)*128 + ((u%32)/16)*64 + gate*16 + (u%16)
DEVI int permn(int n) {
  int g = n >> 10, u = n & 1023;
  return (u >> 5) * 128 + ((u >> 4) & 1) * 64 + g * 16 + (u & 15);
}

__global__ void k_conv_w0(const float* __restrict__ W0, const float* __restrict__ U0,
                          unsigned char* __restrict__ WT) {
  int i = blockIdx.x * 256 + threadIdx.x;            // 4096 * 1152
  if (i >= 4096 * 1152) return;
  int n = i / 1152, k = i - n * 1152;
  float v;
  if (k < 100) v = W0[k * 4096 + n];
  else if (k < 128) v = 0.f;
  else v = U0[(k - 128) * 4096 + n];
  int np = permn(n);
  WT[(size_t)np * 1152 + mapcol(k, np)] = f2fp8(v * SCALE_UP);
}

__global__ void k_conv_w1(const float* __restrict__ W1, const float* __restrict__ U1,
                          unsigned char* __restrict__ WT) {
  int i = blockIdx.x * 256 + threadIdx.x;            // 4096 * 2048
  if (i >= 4096 * 2048) return;
  int n = i >> 11, k = i & 2047;
  float v = (k < 1024) ? W1[k * 4096 + n] : U1[(k - 1024) * 4096 + n];
  int np = permn(n);
  WT[(size_t)np * 2048 + mapcol(k, np)] = f2fp8(v * SCALE_UP);
}

// ---------------- barrier-free per-wave LSTM GEMM pipeline ------------------
// Each wave: private 64x64 output tile, BK=64, private 16 KB LDS double
// buffer, self-staged via global_load_lds, self-synced via s_waitcnt only:
//   stage(0); stage(1);
//   for kb: { vmcnt(8) [vmcnt(0) on last] -> 8x ds_read_b128 -> lgkmcnt(0)
//             -> stage(kb+2) -> 32x mfma }
// vmcnt(8): 8 newer loads (stage kb+1) stay in flight across the wait —
// the fine-grained pipeline a block barrier cannot express. No __syncthreads
// anywhere: no inter-wave data sharing exists.

template<int K1, int KTOT, bool GATHER>
DEVI void lstm_wave(int tile, char* wlds,
    const unsigned char* __restrict__ src1,   // embp (gathered) or h0prev
    const unsigned char* __restrict__ src2,   // h prev (recurrent input)
    const int* __restrict__ idx, int t,
    const unsigned char* __restrict__ WT,     // [4096][KTOT] fp8 perm+mapped
    const float* __restrict__ bias,           // [4096] original layout
    float* __restrict__ cbuf,                 // [2048][1024] fp32, in-place
    unsigned char* __restrict__ hout)         // [2048][1024] fp8 x64, mapped
{
  const int lane = threadIdx.x & 63;
  const int tm = tile & 31;                 // M tiles: 2048/64 = 32
  const int tn = tile >> 5;                 // N tiles: 4096/64 = 64
  const int m0 = tm * 64, n0 = tn * 64;

  const int sr = lane >> 2;                 // staging sub-row 0..15
  const int sc = (lane & 3) * 16;           // staging chunk byte
  const int csw = ((lane & 3) ^ ((lane >> 3) & 3)) * 16;  // gather swizzle

  // per-pass lane offsets (A rows stride 1024, B rows stride KTOT)
  int rowOffA[4], rowOffB[4];
#pragma unroll
  for (int p = 0; p < 4; ++p) {
    rowOffA[p] = (m0 + p * 16 + sr) * 1024 + sc;
    rowOffB[p] = (n0 + p * 16 + sr) * KTOT + sc;
  }
  const unsigned char* g1[4];               // gathered embp rows
  if (GATHER) {
#pragma unroll
    for (int p = 0; p < 4; ++p) {
      int w = idx[(m0 + p * 16 + sr) * 80 + t];
      g1[p] = src1 + (size_t)w * 128 + csw;
    }
  }

  auto stage = [&](int kb) {
    char* la = wlds + (kb & 1) * 4096;
    char* lb = wlds + 8192 + (kb & 1) * 4096;
    const int kc = kb * 64;
    if (GATHER && kc < K1) {
#pragma unroll
      for (int p = 0; p < 4; ++p)
        GLDS16(g1[p] + kc, la + p * 1024 + lane * 16);
    } else {
      const unsigned char* base = (kc < K1) ? (src1 + kc) : (src2 + (kc - K1));
#pragma unroll
      for (int p = 0; p < 4; ++p)
        GLDS16(base + rowOffA[p], la + p * 1024 + lane * 16);
    }
#pragma unroll
    for (int p = 0; p < 4; ++p)
      GLDS16(WT + kc + rowOffB[p], lb + p * 1024 + lane * 16);
  };

  const int cl = lane & 15;
  const int qd = lane >> 4;
  const int fo = (qd ^ ((cl >> 1) & 3)) << 4;
  const int roff = cl * 64 + fo;            // same for A and B buffers

  f4 acc[4][4];
  const f4 fz = {0.f, 0.f, 0.f, 0.f};
#pragma unroll
  for (int a = 0; a < 4; ++a)
#pragma unroll
    for (int b = 0; b < 4; ++b) acc[a][b] = fz;

  constexpr int NKB = KTOT / 64;
  stage(0);
  stage(1);

#pragma unroll 1
  for (int kb = 0; kb < NKB; ++kb) {
    if (kb < NKB - 1)
      asm volatile("s_waitcnt vmcnt(8)" ::: "memory");
    else
      asm volatile("s_waitcnt vmcnt(0)" ::: "memory");
    char* la = wlds + (kb & 1) * 4096;
    char* lb = wlds + 8192 + (kb & 1) * 4096;
    i64x2 av[4], bv[4];
#pragma unroll
    for (int mi = 0; mi < 4; ++mi)
      av[mi] = *(const i64x2*)(la + roff + mi * 1024);
#pragma unroll
    for (int j = 0; j < 4; ++j)
      bv[j] = *(const i64x2*)(lb + roff + j * 1024);
    asm volatile("s_waitcnt lgkmcnt(0)" ::: "memory");
    if (kb + 2 < NKB) stage(kb + 2);        // overwrites buffer just read
#pragma unroll
    for (int mi = 0; mi < 4; ++mi)
#pragma unroll
      for (int j = 0; j < 4; ++j)
        acc[mi][j] = __builtin_amdgcn_mfma_f32_16x16x32_fp8_fp8(
            av[mi][0], bv[j][0], acc[mi][j], 0, 0, 0);
#pragma unroll
    for (int mi = 0; mi < 4; ++mi)
#pragma unroll
      for (int j = 0; j < 4; ++j)
        acc[mi][j] = __builtin_amdgcn_mfma_f32_16x16x32_fp8_fp8(
            av[mi][1], bv[j][1], acc[mi][j], 0, 0, 0);
  }

  // epilogue: per-lane holds z_i, z_f, z_g, z_o (j = gate) for unit u
  const int u = (tn >> 1) * 32 + (tn & 1) * 16 + cl;
  const int hbase = (u & ~63) | (((u >> 5) & 1) << 3) | (u & 7);
  const int c1u = (u >> 3) & 3;
  const float bi = bias[u];
  const float bff = bias[1024 + u];
  const float bg = bias[2048 + u];
  const float bo = bias[3072 + u];
#pragma unroll
  for (int mi = 0; mi < 4; ++mi) {
    int mbase = m0 + mi * 16 + qd * 4;
#pragma unroll
    for (int r = 0; r < 4; ++r) {
      int m = mbase + r;
      float gi = sigmoidf_(acc[mi][0][r] * SCALE_DN + bi);
      float gf = sigmoidf_(acc[mi][1][r] * SCALE_DN + bff);
      float gg = tanhf_(acc[mi][2][r] * SCALE_DN + bg);
      float go = tanhf_ /*placeholder*/ (0.f);
      go = sigmoidf_(acc[mi][3][r] * SCALE_DN + bo);
      size_t coff = (size_t)m * 1024 + u;
      float cn = gf * cbuf[coff] + gi * gg;
      cbuf[coff] = cn;
      int c2 = c1u ^ ((qd * 2 + (r >> 1)) & 3);
      hout[(size_t)m * 1024 + (hbase | (c2 << 4))] =
          f2fp8(go * tanhf_(cn) * SCALE_UP);
    }
  }
}

// mode 0: layer-0 only, grid 1024 (wave tile = blk*2+v).
// mode 1: fused, grid 2048: wave 0 = layer-1(t-1) tile blk, wave 1 =
//         layer-0(t) tile blk (one long + one short wave per block).
// mode 2: layer-1 only, grid 1024.
__global__ __launch_bounds__(128, 2) void k_step(
    int mode,
    const unsigned char* embp, const unsigned char* h0in,
    const int* idx, int t,
    const unsigned char* WT0, const float* b0, float* c0, unsigned char* h0out,
    const unsigned char* h0prev, const unsigned char* h1in,
    const unsigned char* WT1, const float* b1, float* c1, unsigned char* h1out)
{
  extern __shared__ char smem[];
  const int v = threadIdx.x >> 6;
  char* wlds = smem + v * 16384;
  if (mode == 1) {
    if (v == 0)
      lstm_wave<1024, 2048, false>(blockIdx.x, wlds, h0prev, h1in, nullptr, 0,
                                   WT1, b1, c1, h1out);
    else
      lstm_wave<128, 1152, true>(blockIdx.x, wlds, embp, h0in, idx, t,
                                 WT0, b0, c0, h0out);
  } else if (mode == 0) {
    lstm_wave<128, 1152, true>(blockIdx.x * 2 + v, wlds, embp, h0in, idx, t,
                               WT0, b0, c0, h0out);
  } else {
    lstm_wave<1024, 2048, false>(blockIdx.x * 2 + v, wlds, h0prev, h1in,
                                 nullptr, 0, WT1, b1, c1, h1out);
  }
}

// ---------------- final FC + sigmoid (r6) ----------------

__global__ void k_fc(const unsigned char* __restrict__ h1,
                     const float* __restrict__ fcW, const float* __restrict__ fcb,
                     float* __restrict__ out) {
  int wv = threadIdx.x >> 6;
  int lane = threadIdx.x & 63;
  int row = blockIdx.x * 4 + wv;
  if (row >= 2048) return;
  const unsigned char* hr = h1 + (size_t)row * 1024;
  float s = 0.f;
  for (int k = lane; k < 1024; k += 64)
    s += fp82f(hr[mapcol(k, row)]) * fcW[k];
#pragma unroll
  for (int off = 32; off > 0; off >>= 1) s += __shfl_down(s, off);
  if (lane == 0) out[row] = sigmoidf_(s * (1.0f / SCALE_UP) + fcb[0]);
}

// ---------------- launcher ----------------

extern "C" void kernel_launch(void* const* d_in, const int* in_sizes, int n_in,
                              void* d_out, int out_size, void* d_ws, size_t ws_size,
                              hipStream_t stream) {
  const int*   idx = (const int*)d_in[0];
  const float* emb = (const float*)d_in[1];
  const float* W0  = (const float*)d_in[2];
  const float* U0  = (const float*)d_in[3];
  const float* b0  = (const float*)d_in[4];
  const float* W1  = (const float*)d_in[5];
  const float* U1  = (const float*)d_in[6];
  const float* b1  = (const float*)d_in[7];
  const float* fcW = (const float*)d_in[8];
  const float* fcb = (const float*)d_in[9];
  float* out = (float*)d_out;

  char* ws = (char*)d_ws;
  unsigned char* embp = (unsigned char*)(ws);                   //  1,280,000
  unsigned char* WT0  = (unsigned char*)(ws + 1280000);         //  4,718,592
  unsigned char* WT1  = (unsigned char*)(ws + 5998592);         //  8,388,608
  unsigned char* h0b[2] = {(unsigned char*)(ws + 14387200),
                           (unsigned char*)(ws + 16484352)};    // 2x 2,097,152
  unsigned char* h1b[2] = {(unsigned char*)(ws + 18581504),
                           (unsigned char*)(ws + 20678656)};    // 2x 2,097,152
  float* c0 = (float*)(ws + 22775808);                          //  8,388,608
  float* c1 = (float*)(ws + 31164416);                          //  8,388,608
  // total: 39,553,024 bytes

  // zero h (4 buffers) and c0/c1 — contiguous region
  hipMemsetAsync(ws + 14387200, 0, 25165824, stream);

  k_conv_emb<<<5000, 256, 0, stream>>>(emb, embp);
  k_conv_w0<<<18432, 256, 0, stream>>>(W0, U0, WT0);
  k_conv_w1<<<32768, 256, 0, stream>>>(W1, U1, WT1);

  // t = 0: layer-0 only
  k_step<<<1024, 128, 32768, stream>>>(0, embp, h0b[1], idx, 0,
                                       WT0, b0, c0, h0b[0],
                                       nullptr, nullptr, WT1, b1, c1, nullptr);
  // t = 1..79: fused [layer-1(t-1) | layer-0(t)]
  for (int t = 1; t < 80; ++t) {
    k_step<<<2048, 128, 32768, stream>>>(1, embp, h0b[(t + 1) & 1], idx, t,
                                         WT0, b0, c0, h0b[t & 1],
                                         h0b[(t - 1) & 1], h1b[t & 1],
                                         WT1, b1, c1, h1b[(t + 1) & 1]);
  }
  // final: layer-1 at t=79 (src1 = h0b[1], in h1b[0], out h1b[1])
  k_step<<<1024, 128, 32768, stream>>>(2, nullptr, nullptr, nullptr, 0,
                                       WT0, b0, c0, nullptr,
                                       h0b[1], h1b[0], WT1, b1, c1, h1b[1]);

  k_fc<<<512, 256, 0, stream>>>(h1b[1], fcW, fcb, out);
}